// Round 2
// baseline (8265.921 us; speedup 1.0000x reference)
//
#include <hip/hip_runtime.h>
#include <hip/hip_cooperative_groups.h>
#include <math.h>

namespace cg = cooperative_groups;

// LSTM: B=128, T=256, D=256, H=1024, C=10
// Round 3: persistent cooperative kernel — all 256 steps in ONE launch.
//   - Weights register-resident: each of 8 waves (4 gates x 2 K-halves) holds
//     its 20 k-tiles x 2 B-streams = 160 VGPRs, loaded ONCE. K-loop has zero
//     global loads (was: full 10.5 MB Wpack re-read from L2 every step).
//   - c-state in a per-thread register for all 256 steps (owner thread is
//     fixed), eliminating the 1 MB/step global round-trip.
//   - grid.sync() between steps (device-scope fences give cross-XCD h
//     visibility) replaces 256 kernel launches.
//   Grid (32,8) x 512 = 256 blocks = 1 block/CU, 2 waves/SIMD,
//   __launch_bounds__(512,2) caps at 256 VGPR so co-residency is guaranteed.
// Workspace layout:
//   [0)          Wpack  bf16  10,485,760 B
//   [10485760)   xT     bf16  16,777,216 B   ([T][B][D], x transposed+cast)
//   [27262976)   h0     bf16     262,144 B
//   [27525120)   h1     bf16     262,144 B

#define BB 128
#define TT 256
#define DD 256
#define HH 1024
#define NKT 40   // 1280 / 32 k-tiles
#define KHT 20   // k-tiles per K-half wave

typedef __bf16 bf16x8 __attribute__((ext_vector_type(8)));
typedef float  f32x4  __attribute__((ext_vector_type(4)));
typedef unsigned short u16;
typedef u16 u16x8 __attribute__((ext_vector_type(8)));

__device__ __forceinline__ u16 f2bf(float f){
  unsigned u = __builtin_bit_cast(unsigned, f);
  u += 0x7fffu + ((u >> 16) & 1u);            // round-to-nearest-even
  return (u16)(u >> 16);
}
__device__ __forceinline__ float bf2f(u16 b){
  unsigned u = ((unsigned)b) << 16;
  return __builtin_bit_cast(float, u);
}
__device__ __forceinline__ float sigm(float x){
  return 1.f / (1.f + __expf(-x));
}
__device__ __forceinline__ float tanh_fast(float x){
  return 2.f / (1.f + __expf(-2.f * x)) - 1.f;
}

// ---- pack weights into MFMA B-fragment order -------------------------------
// Wpack[ct][kt][lane][j]: ct in [0,256) covers gate-cols [ct*16, ct*16+16)
// (col = gate*1024 + n); element = W[k = kt*32 + (lane>>4)*8 + j][col = ct*16 + (lane&15)]
__global__ void prep_wpack(const float* __restrict__ Wfx, const float* __restrict__ Wix,
                           const float* __restrict__ Wgx, const float* __restrict__ Wox,
                           const float* __restrict__ Wfh, const float* __restrict__ Wih,
                           const float* __restrict__ Wgh, const float* __restrict__ Woh,
                           u16* __restrict__ Wpack){
  int id = blockIdx.x * 256 + threadIdx.x;    // [0, 655360)
  int lane = id & 63;
  int kt = (id >> 6) % NKT;
  int ct = id / (64 * NKT);
  int col = ct * 16 + (lane & 15);
  int g = col >> 10, n = col & 1023;
  int kbase = kt * 32 + (lane >> 4) * 8;
  const float* Wx = (g==0) ? Wfx : (g==1) ? Wix : (g==2) ? Wgx : Wox;
  const float* Wh = (g==0) ? Wfh : (g==1) ? Wih : (g==2) ? Wgh : Woh;
  u16x8 v;
  #pragma unroll
  for (int j = 0; j < 8; ++j){
    int k = kbase + j;
    float f = (k < DD) ? Wx[k * HH + n] : Wh[(k - DD) * HH + n];
    v[j] = f2bf(f);
  }
  *(u16x8*)(Wpack + (size_t)id * 8) = v;      // dst index == id (by construction)
}

// ---- transpose+cast x: xT[t][b][d] = bf16(x[b][t][d]) ----------------------
__global__ void prep_xT(const float* __restrict__ x, u16* __restrict__ xT){
  int id = blockIdx.x * 256 + threadIdx.x;    // [0, 1048576), 8 elems each
  int t = id >> 12;
  int b = (id >> 5) & 127;
  int d0 = (id & 31) * 8;
  const float* src = x + ((size_t)b * TT + t) * DD + d0;
  u16x8 v;
  #pragma unroll
  for (int j = 0; j < 8; ++j) v[j] = f2bf(src[j]);
  *(u16x8*)(xT + (size_t)id * 8) = v;
}

// ---- ALL 256 LSTM steps in one persistent cooperative kernel ---------------
__global__ __launch_bounds__(512, 2) void lstm_persist(
    const u16* __restrict__ xT,    // [T][B][D] bf16
    const u16* __restrict__ Wpack,
    u16* __restrict__ h0,          // [128][1024] bf16 (even-t input)
    u16* __restrict__ h1,          // [128][1024] bf16
    const float* __restrict__ bfv, const float* __restrict__ biv,
    const float* __restrict__ bgv, const float* __restrict__ bov){
  cg::grid_group grid = cg::this_grid();
  __shared__ u16x8 As4[NKT * 64];  // 40 KB: A tile in fragment order
  __shared__ float gLds[16][132];  // gate exchange (8.25 KB)
  __shared__ float pLds[16][132];  // K-half partial-sum exchange (8.25 KB)
  const int tid = threadIdx.x;
  const int n0 = blockIdx.x * 32;  // hidden-unit tile
  const int m0 = blockIdx.y * 16;  // batch-row tile

  const int w = tid >> 6, lane = tid & 63, cr = lane & 15, q4 = lane >> 4;
  const int g  = w & 3;            // gate
  const int kh = w >> 2;           // K-half: kt in [kh*20, kh*20+20)
  const int ktBeg = kh * KHT;

  // ---- load this wave's weights into registers ONCE (160 VGPRs) ----
  const size_t ct0 = (size_t)(g * 64 + blockIdx.x * 2);  // 2 col-tiles of gate g
  const u16x8* Wp = (const u16x8*)Wpack;
  const u16x8* wq0 = Wp + ct0 * NKT * 64 + lane;
  const u16x8* wq1 = wq0 + NKT * 64;
  u16x8 wr0[KHT], wr1[KHT];
  #pragma unroll
  for (int i = 0; i < KHT; ++i){
    wr0[i] = wq0[(size_t)(ktBeg + i) * 64];
    wr1[i] = wq1[(size_t)(ktBeg + i) * 64];
  }

  // bias (used by kh==0 waves in the combine)
  const float* bptr = (g==0) ? bfv : (g==1) ? biv : (g==2) ? bgv : bov;
  const float bias0 = bptr[n0 + cr], bias1 = bptr[n0 + 16 + cr];

  // ---- fixed per-thread staging geometry ----
  // chunk ch -> row m = ch/160, k0 = (ch%160)*8 ; frag slot = kt*64 + 16*q + m
  int soff[5], sdst[5];
  unsigned isx = 0;
  #pragma unroll
  for (int it = 0; it < 5; ++it){
    int ch = tid + it * 512;
    int m = ch / 160;
    int k0 = (ch - m * 160) * 8;
    if (k0 < DD){ soff[it] = (m0 + m) * DD + k0; isx |= (1u << it); }
    else        { soff[it] = (m0 + m) * HH + (k0 - DD); }
    sdst[it] = (k0 >> 5) * 64 + 16 * ((k0 >> 3) & 3) + m;
  }

  // cell-update ownership is fixed: c lives in a register for all 256 steps
  const int crow = tid >> 5, cnn = tid & 31;
  const int gi = (m0 + crow) * HH + n0 + cnn;
  float cstate = 0.f;

  #pragma unroll 1
  for (int t = 0; t < TT; ++t){
    const u16* xTt  = xT + (size_t)t * BB * DD;
    const u16* hin  = (t & 1) ? h1 : h0;
    u16*       hout = (t & 1) ? h0 : h1;

    // stage A = [x_t rows | h rows] into LDS in MFMA A-fragment order
    #pragma unroll
    for (int it = 0; it < 5; ++it){
      const u16* base = ((isx >> it) & 1) ? xTt : hin;
      As4[sdst[it]] = *(const u16x8*)(base + soff[it]);
    }
    __syncthreads();

    f32x4 acc0 = {0.f, 0.f, 0.f, 0.f}, acc1 = {0.f, 0.f, 0.f, 0.f};
    u16x8 aP0 = As4[ktBeg * 64 + lane];
    u16x8 aP1 = As4[(ktBeg + 1) * 64 + lane];
    #pragma unroll
    for (int kt = 0; kt < KHT; ++kt){
      u16x8 ac = (kt & 1) ? aP1 : aP0;
      if (kt + 2 < KHT){
        if (kt & 1) aP1 = As4[(ktBeg + kt + 2) * 64 + lane];
        else        aP0 = As4[(ktBeg + kt + 2) * 64 + lane];
      }
      acc0 = __builtin_amdgcn_mfma_f32_16x16x32_bf16(__builtin_bit_cast(bf16x8, ac),
               __builtin_bit_cast(bf16x8, wr0[kt]), acc0, 0, 0, 0);
      acc1 = __builtin_amdgcn_mfma_f32_16x16x32_bf16(__builtin_bit_cast(bf16x8, ac),
               __builtin_bit_cast(bf16x8, wr1[kt]), acc1, 0, 0, 0);
    }

    // combine K-halves (C/D layout: col=lane&15, row=q4*4+r)
    if (kh){
      #pragma unroll
      for (int r = 0; r < 4; ++r){
        pLds[q4 * 4 + r][g * 32 + cr]      = acc0[r];
        pLds[q4 * 4 + r][g * 32 + 16 + cr] = acc1[r];
      }
    }
    __syncthreads();
    if (!kh){
      #pragma unroll
      for (int r = 0; r < 4; ++r){
        gLds[q4 * 4 + r][g * 32 + cr] =
            acc0[r] + pLds[q4 * 4 + r][g * 32 + cr] + bias0;
        gLds[q4 * 4 + r][g * 32 + 16 + cr] =
            acc1[r] + pLds[q4 * 4 + r][g * 32 + 16 + cr] + bias1;
      }
    }
    __syncthreads();

    // fused LSTM cell update: 512 (row, hidden) units, 1 per thread
    {
      float fp = gLds[crow][cnn],      ip = gLds[crow][32 + cnn];
      float gp = gLds[crow][64 + cnn], op = gLds[crow][96 + cnn];
      float fs = sigm(fp);
      float is = sigm(ip);
      float gs = tanh_fast(gp);
      float os = sigm(op);
      cstate = gs * is + cstate * fs;
      hout[gi] = f2bf(tanh_fast(cstate) * os);
    }

    grid.sync();   // h visible across XCDs for the next step
  }
}

// ---- out[b][c] = h_T[b] . Wph[:,c] + bp[c] ---------------------------------
__global__ void final_proj(const u16* __restrict__ h, const float* __restrict__ Wph,
                           const float* __restrict__ bp, float* __restrict__ out){
  __shared__ float red[10][256];
  int b = blockIdx.x, tid = threadIdx.x;
  float p[10];
  #pragma unroll
  for (int c = 0; c < 10; ++c) p[c] = 0.f;
  for (int k = tid; k < HH; k += 256){
    float hv = bf2f(h[b * HH + k]);
    const float* wr = Wph + (size_t)k * 10;
    #pragma unroll
    for (int c = 0; c < 10; ++c) p[c] += hv * wr[c];
  }
  #pragma unroll
  for (int c = 0; c < 10; ++c) red[c][tid] = p[c];
  __syncthreads();
  for (int s = 128; s > 0; s >>= 1){
    if (tid < s){
      #pragma unroll
      for (int c = 0; c < 10; ++c) red[c][tid] += red[c][tid + s];
    }
    __syncthreads();
  }
  if (tid < 10) out[b * 10 + tid] = red[tid][0] + bp[tid];
}

extern "C" void kernel_launch(void* const* d_in, const int* in_sizes, int n_in,
                              void* d_out, int out_size, void* d_ws, size_t ws_size,
                              hipStream_t stream){
  (void)in_sizes; (void)n_in; (void)out_size; (void)ws_size;
  const float* x   = (const float*)d_in[0];
  const float* Wfx = (const float*)d_in[1];
  const float* Wix = (const float*)d_in[2];
  const float* Wgx = (const float*)d_in[3];
  const float* Wox = (const float*)d_in[4];
  const float* Wfh = (const float*)d_in[5];
  const float* Wih = (const float*)d_in[6];
  const float* Wgh = (const float*)d_in[7];
  const float* Woh = (const float*)d_in[8];
  const float* bfv = (const float*)d_in[9];
  const float* biv = (const float*)d_in[10];
  const float* bgv = (const float*)d_in[11];
  const float* bov = (const float*)d_in[12];
  const float* Wph = (const float*)d_in[13];
  const float* bp  = (const float*)d_in[14];

  char* ws = (char*)d_ws;
  u16*  Wpack = (u16*)ws;                    // 10,485,760 B
  u16*  xT    = (u16*)(ws + 10485760);       // 16,777,216 B
  u16*  h0    = (u16*)(ws + 27262976);       //    262,144 B
  u16*  h1    = (u16*)(ws + 27525120);       //    262,144 B

  prep_wpack<<<2560, 256, 0, stream>>>(Wfx, Wix, Wgx, Wox, Wfh, Wih, Wgh, Woh, Wpack);
  prep_xT<<<4096, 256, 0, stream>>>(x, xT);
  hipMemsetAsync(h0, 0, 262144, stream);

  void* args[] = {(void*)&xT, (void*)&Wpack, (void*)&h0, (void*)&h1,
                  (void*)&bfv, (void*)&biv, (void*)&bgv, (void*)&bov};
  hipLaunchCooperativeKernel((const void*)lstm_persist, dim3(32, 8), dim3(512),
                             args, 0, stream);

  // t=255 (odd) wrote h0 -> final hidden state lives in h0
  final_proj<<<128, 256, 0, stream>>>(h0, Wph, bp, (float*)d_out);
}

// Round 3
// 3938.176 us; speedup vs baseline: 2.0989x; 2.0989x over previous
//
#include <hip/hip_runtime.h>
#include <math.h>

// LSTM: B=128, T=256, D=256, H=1024, C=10
// Round 4: persistent kernel, fixed.
//   Round-3 post-mortem (counters): VGPR=116 -> the 160 weight VGPRs spilled
//   to scratch because cg::grid_sync is a non-inlined call (WRITE 67.5MB =
//   spill stores; 337MB HBM FETCH = scratch reloads thrashing L2).
//   SQ_LDS_BANK_CONFLICT=1.47e8 = staging ds_write_b128 64-way conflict
//   (all lanes -> banks 0-3).
//   Fixes:
//   - Hand-rolled per-row-group barrier (8 groups x 32 blocks sharing
//     blockIdx.y — batch rows are independent, h only flows within a group).
//     All inline builtins -> no call -> weights stay register-resident.
//     Cooperative launch kept only for the co-residency guarantee.
//   - XOR-swizzled As4 layout: slot ^= ((slot>>6)&7) ^ (((slot>>4)&1)<<2).
//     Bijective; staging writes spread across bank groups; A-frag reads
//     (uniform kt per wave) stay conflict-free.
//   Grid (32,8) x 512 thr, 1 block/CU, 2 waves/SIMD, launch_bounds(512,2).
// Workspace layout:
//   [0)          Wpack  bf16  10,485,760 B
//   [10485760)   xT     bf16  16,777,216 B   ([T][B][D], x transposed+cast)
//   [27262976)   h0     bf16     262,144 B
//   [27525120)   h1     bf16     262,144 B
//   [27787264)   barCnt u32        1,024 B   (8 groups x 128B stride)

#define BB 128
#define TT 256
#define DD 256
#define HH 1024
#define NKT 40   // 1280 / 32 k-tiles
#define KHT 20   // k-tiles per K-half wave

typedef __bf16 bf16x8 __attribute__((ext_vector_type(8)));
typedef float  f32x4  __attribute__((ext_vector_type(4)));
typedef unsigned short u16;
typedef u16 u16x8 __attribute__((ext_vector_type(8)));

__device__ __forceinline__ u16 f2bf(float f){
  unsigned u = __builtin_bit_cast(unsigned, f);
  u += 0x7fffu + ((u >> 16) & 1u);            // round-to-nearest-even
  return (u16)(u >> 16);
}
__device__ __forceinline__ float bf2f(u16 b){
  unsigned u = ((unsigned)b) << 16;
  return __builtin_bit_cast(float, u);
}
__device__ __forceinline__ float sigm(float x){
  return 1.f / (1.f + __expf(-x));
}
__device__ __forceinline__ float tanh_fast(float x){
  return 2.f / (1.f + __expf(-2.f * x)) - 1.f;
}
// LDS A-tile swizzle: breaks the staging-write 64-way bank conflict.
// slot bits: m=[0:3], q=[4:5], kt=[6:11]. XOR low-3 bits with f(kt, q&1).
// Involution (mask bits unchanged by XOR) -> bijective.
__device__ __forceinline__ int swz(int slot){
  return slot ^ ((slot >> 6) & 7) ^ (((slot >> 4) & 1) << 2);
}

// ---- pack weights into MFMA B-fragment order -------------------------------
// Wpack[ct][kt][lane][j]: ct in [0,256) covers gate-cols [ct*16, ct*16+16)
// (col = gate*1024 + n); element = W[k = kt*32 + (lane>>4)*8 + j][col = ct*16 + (lane&15)]
__global__ void prep_wpack(const float* __restrict__ Wfx, const float* __restrict__ Wix,
                           const float* __restrict__ Wgx, const float* __restrict__ Wox,
                           const float* __restrict__ Wfh, const float* __restrict__ Wih,
                           const float* __restrict__ Wgh, const float* __restrict__ Woh,
                           u16* __restrict__ Wpack){
  int id = blockIdx.x * 256 + threadIdx.x;    // [0, 655360)
  int lane = id & 63;
  int kt = (id >> 6) % NKT;
  int ct = id / (64 * NKT);
  int col = ct * 16 + (lane & 15);
  int g = col >> 10, n = col & 1023;
  int kbase = kt * 32 + (lane >> 4) * 8;
  const float* Wx = (g==0) ? Wfx : (g==1) ? Wix : (g==2) ? Wgx : Wox;
  const float* Wh = (g==0) ? Wfh : (g==1) ? Wih : (g==2) ? Wgh : Woh;
  u16x8 v;
  #pragma unroll
  for (int j = 0; j < 8; ++j){
    int k = kbase + j;
    float f = (k < DD) ? Wx[k * HH + n] : Wh[(k - DD) * HH + n];
    v[j] = f2bf(f);
  }
  *(u16x8*)(Wpack + (size_t)id * 8) = v;      // dst index == id (by construction)
}

// ---- transpose+cast x: xT[t][b][d] = bf16(x[b][t][d]) ----------------------
__global__ void prep_xT(const float* __restrict__ x, u16* __restrict__ xT){
  int id = blockIdx.x * 256 + threadIdx.x;    // [0, 1048576), 8 elems each
  int t = id >> 12;
  int b = (id >> 5) & 127;
  int d0 = (id & 31) * 8;
  const float* src = x + ((size_t)b * TT + t) * DD + d0;
  u16x8 v;
  #pragma unroll
  for (int j = 0; j < 8; ++j) v[j] = f2bf(src[j]);
  *(u16x8*)(xT + (size_t)id * 8) = v;
}

// ---- ALL 256 LSTM steps in one persistent cooperative kernel ---------------
__global__ __launch_bounds__(512, 2) void lstm_persist(
    const u16* __restrict__ xT,    // [T][B][D] bf16
    const u16* __restrict__ Wpack,
    u16* __restrict__ h0,          // [128][1024] bf16 (even-t input)
    u16* __restrict__ h1,          // [128][1024] bf16
    const float* __restrict__ bfv, const float* __restrict__ biv,
    const float* __restrict__ bgv, const float* __restrict__ bov,
    unsigned* __restrict__ barCnt){
  __shared__ u16x8 As4[NKT * 64];  // 40 KB: A tile in fragment order (swizzled)
  __shared__ float gLds[16][132];  // gate exchange (8.25 KB)
  __shared__ float pLds[16][132];  // K-half partial-sum exchange (8.25 KB)
  const int tid = threadIdx.x;
  const int n0 = blockIdx.x * 32;  // hidden-unit tile
  const int m0 = blockIdx.y * 16;  // batch-row tile
  unsigned* const myCnt = barCnt + blockIdx.y * 32;  // group barrier counter

  const int w = tid >> 6, lane = tid & 63, cr = lane & 15, q4 = lane >> 4;
  const int g  = w & 3;            // gate
  const int kh = w >> 2;           // K-half: kt in [kh*20, kh*20+20)
  const int ktBeg = kh * KHT;

  // ---- load this wave's weights into registers ONCE (160 VGPRs) ----
  const size_t ct0 = (size_t)(g * 64 + blockIdx.x * 2);  // 2 col-tiles of gate g
  const u16x8* Wp = (const u16x8*)Wpack;
  const u16x8* wq0 = Wp + ct0 * NKT * 64 + lane;
  const u16x8* wq1 = wq0 + NKT * 64;
  u16x8 wr0[KHT], wr1[KHT];
  #pragma unroll
  for (int i = 0; i < KHT; ++i){
    wr0[i] = wq0[(size_t)(ktBeg + i) * 64];
    wr1[i] = wq1[(size_t)(ktBeg + i) * 64];
  }

  // bias (used by kh==0 waves in the combine)
  const float* bptr = (g==0) ? bfv : (g==1) ? biv : (g==2) ? bgv : bov;
  const float bias0 = bptr[n0 + cr], bias1 = bptr[n0 + 16 + cr];

  // ---- fixed per-thread staging geometry ----
  // chunk ch -> row m = ch/160, k0 = (ch%160)*8 ; frag slot = kt*64 + 16*q + m
  int soff[5], sdst[5];
  unsigned isx = 0;
  #pragma unroll
  for (int it = 0; it < 5; ++it){
    int ch = tid + it * 512;
    int m = ch / 160;
    int k0 = (ch - m * 160) * 8;
    if (k0 < DD){ soff[it] = (m0 + m) * DD + k0; isx |= (1u << it); }
    else        { soff[it] = (m0 + m) * HH + (k0 - DD); }
    sdst[it] = swz((k0 >> 5) * 64 + 16 * ((k0 >> 3) & 3) + m);
  }

  // cell-update ownership is fixed: c lives in a register for all 256 steps
  const int crow = tid >> 5, cnn = tid & 31;
  const int gi = (m0 + crow) * HH + n0 + cnn;
  float cstate = 0.f;

  #pragma unroll 1
  for (int t = 0; t < TT; ++t){
    const u16* xTt  = xT + (size_t)t * BB * DD;
    const u16* hin  = (t & 1) ? h1 : h0;
    u16*       hout = (t & 1) ? h0 : h1;

    // stage A = [x_t rows | h rows] into LDS in MFMA A-fragment order
    #pragma unroll
    for (int it = 0; it < 5; ++it){
      const u16* base = ((isx >> it) & 1) ? xTt : hin;
      As4[sdst[it]] = *(const u16x8*)(base + soff[it]);
    }
    __syncthreads();

    f32x4 acc0 = {0.f, 0.f, 0.f, 0.f}, acc1 = {0.f, 0.f, 0.f, 0.f};
    u16x8 aP0 = As4[swz(ktBeg * 64 + lane)];
    u16x8 aP1 = As4[swz((ktBeg + 1) * 64 + lane)];
    #pragma unroll
    for (int kt = 0; kt < KHT; ++kt){
      u16x8 ac = (kt & 1) ? aP1 : aP0;
      if (kt + 2 < KHT){
        if (kt & 1) aP1 = As4[swz((ktBeg + kt + 2) * 64 + lane)];
        else        aP0 = As4[swz((ktBeg + kt + 2) * 64 + lane)];
      }
      acc0 = __builtin_amdgcn_mfma_f32_16x16x32_bf16(__builtin_bit_cast(bf16x8, ac),
               __builtin_bit_cast(bf16x8, wr0[kt]), acc0, 0, 0, 0);
      acc1 = __builtin_amdgcn_mfma_f32_16x16x32_bf16(__builtin_bit_cast(bf16x8, ac),
               __builtin_bit_cast(bf16x8, wr1[kt]), acc1, 0, 0, 0);
    }

    // combine K-halves (C/D layout: col=lane&15, row=q4*4+r)
    if (kh){
      #pragma unroll
      for (int r = 0; r < 4; ++r){
        pLds[q4 * 4 + r][g * 32 + cr]      = acc0[r];
        pLds[q4 * 4 + r][g * 32 + 16 + cr] = acc1[r];
      }
    }
    __syncthreads();
    if (!kh){
      #pragma unroll
      for (int r = 0; r < 4; ++r){
        gLds[q4 * 4 + r][g * 32 + cr] =
            acc0[r] + pLds[q4 * 4 + r][g * 32 + cr] + bias0;
        gLds[q4 * 4 + r][g * 32 + 16 + cr] =
            acc1[r] + pLds[q4 * 4 + r][g * 32 + 16 + cr] + bias1;
      }
    }
    __syncthreads();

    // fused LSTM cell update: 512 (row, hidden) units, 1 per thread
    {
      float fp = gLds[crow][cnn],      ip = gLds[crow][32 + cnn];
      float gp = gLds[crow][64 + cnn], op = gLds[crow][96 + cnn];
      float fs = sigm(fp);
      float is = sigm(ip);
      float gs = tanh_fast(gp);
      float os = sigm(op);
      cstate = gs * is + cstate * fs;
      hout[gi] = f2bf(tanh_fast(cstate) * os);
    }

    // ---- per-row-group barrier (32 blocks sharing blockIdx.y) ----
    // h only flows within a group; monotonic counter, device-scope atomics.
    if (t != TT - 1){
      __syncthreads();               // drains this block's hout stores (vmcnt 0)
      if (tid == 0){
        __threadfence();             // release: writeback so peers see hout
        __hip_atomic_fetch_add(myCnt, 1u, __ATOMIC_RELAXED,
                               __HIP_MEMORY_SCOPE_AGENT);
        const unsigned tgt = (unsigned)(t + 1) * 32u;
        while (__hip_atomic_load(myCnt, __ATOMIC_RELAXED,
                                 __HIP_MEMORY_SCOPE_AGENT) < tgt)
          __builtin_amdgcn_s_sleep(1);
        __threadfence();             // acquire: invalidate stale h
      }
      __syncthreads();
    }
  }
}

// ---- out[b][c] = h_T[b] . Wph[:,c] + bp[c] ---------------------------------
__global__ void final_proj(const u16* __restrict__ h, const float* __restrict__ Wph,
                           const float* __restrict__ bp, float* __restrict__ out){
  __shared__ float red[10][256];
  int b = blockIdx.x, tid = threadIdx.x;
  float p[10];
  #pragma unroll
  for (int c = 0; c < 10; ++c) p[c] = 0.f;
  for (int k = tid; k < HH; k += 256){
    float hv = bf2f(h[b * HH + k]);
    const float* wr = Wph + (size_t)k * 10;
    #pragma unroll
    for (int c = 0; c < 10; ++c) p[c] += hv * wr[c];
  }
  #pragma unroll
  for (int c = 0; c < 10; ++c) red[c][tid] = p[c];
  __syncthreads();
  for (int s = 128; s > 0; s >>= 1){
    if (tid < s){
      #pragma unroll
      for (int c = 0; c < 10; ++c) red[c][tid] += red[c][tid + s];
    }
    __syncthreads();
  }
  if (tid < 10) out[b * 10 + tid] = red[tid][0] + bp[tid];
}

extern "C" void kernel_launch(void* const* d_in, const int* in_sizes, int n_in,
                              void* d_out, int out_size, void* d_ws, size_t ws_size,
                              hipStream_t stream){
  (void)in_sizes; (void)n_in; (void)out_size; (void)ws_size;
  const float* x   = (const float*)d_in[0];
  const float* Wfx = (const float*)d_in[1];
  const float* Wix = (const float*)d_in[2];
  const float* Wgx = (const float*)d_in[3];
  const float* Wox = (const float*)d_in[4];
  const float* Wfh = (const float*)d_in[5];
  const float* Wih = (const float*)d_in[6];
  const float* Wgh = (const float*)d_in[7];
  const float* Woh = (const float*)d_in[8];
  const float* bfv = (const float*)d_in[9];
  const float* biv = (const float*)d_in[10];
  const float* bgv = (const float*)d_in[11];
  const float* bov = (const float*)d_in[12];
  const float* Wph = (const float*)d_in[13];
  const float* bp  = (const float*)d_in[14];

  char* ws = (char*)d_ws;
  u16*  Wpack = (u16*)ws;                    // 10,485,760 B
  u16*  xT    = (u16*)(ws + 10485760);       // 16,777,216 B
  u16*  h0    = (u16*)(ws + 27262976);       //    262,144 B
  u16*  h1    = (u16*)(ws + 27525120);       //    262,144 B
  unsigned* barCnt = (unsigned*)(ws + 27787264);  // 1,024 B

  prep_wpack<<<2560, 256, 0, stream>>>(Wfx, Wix, Wgx, Wox, Wfh, Wih, Wgh, Woh, Wpack);
  prep_xT<<<4096, 256, 0, stream>>>(x, xT);
  hipMemsetAsync(h0, 0, 262144, stream);
  hipMemsetAsync(barCnt, 0, 1024, stream);

  void* args[] = {(void*)&xT, (void*)&Wpack, (void*)&h0, (void*)&h1,
                  (void*)&bfv, (void*)&biv, (void*)&bgv, (void*)&bov,
                  (void*)&barCnt};
  hipLaunchCooperativeKernel((const void*)lstm_persist, dim3(32, 8), dim3(512),
                             args, 0, stream);

  // t=255 (odd) wrote h0 -> final hidden state lives in h0
  final_proj<<<128, 256, 0, stream>>>(h0, Wph, bp, (float*)d_out);
}

// Round 4
// 3811.161 us; speedup vs baseline: 2.1689x; 1.0333x over previous
//
#include <hip/hip_runtime.h>
#include <math.h>

// LSTM: B=128, T=256, D=256, H=1024, C=10
// Round 5: persistent kernel — kill the weight spill (rule #20).
//   Round-4 post-mortem: VGPR=116 with the call-free barrier -> the spill was
//   NEVER the cg call. wr0[20]/wr1[20] are runtime-indexed arrays at SROA
//   time (full unroll happens later), so they live in scratch (320 B local,
//   the exact r286 signature). Every step re-loads 640 B/thread of weights
//   through a thrashing L1 -> ~15 us/step, MfmaUtil 3.5%.
//   WRITE_SIZE 67.5 MB == hout traffic (not spills); FETCH 337 MB == h/xT
//   refetch after the per-step L2-invalidating acquire (cheap, ~1.3 MB/step).
//   Fixes:
//   - 40 NAMED u16x8 weight registers via X-macro + fully macro-unrolled
//     K-loop: every access is a distinct SSA value, SROA cannot demote.
//   - Named staging geometry scalars (same rule-#20 protection).
//   - Next-step x staged early (x is h-independent) to overlap the barrier.
//   Grid (32,8) x 512 thr, 1 block/CU, 2 waves/SIMD, launch_bounds(512,2)
//   -> 256 VGPR cap; demand ~210.
// Workspace layout:
//   [0)          Wpack  bf16  10,485,760 B
//   [10485760)   xT     bf16  16,777,216 B   ([T][B][D], x transposed+cast)
//   [27262976)   h0     bf16     262,144 B
//   [27525120)   h1     bf16     262,144 B
//   [27787264)   barCnt u32        1,024 B   (8 groups x 128B stride)

#define BB 128
#define TT 256
#define DD 256
#define HH 1024
#define NKT 40   // 1280 / 32 k-tiles
#define KHT 20   // k-tiles per K-half wave

typedef __bf16 bf16x8 __attribute__((ext_vector_type(8)));
typedef float  f32x4  __attribute__((ext_vector_type(4)));
typedef unsigned short u16;
typedef u16 u16x8 __attribute__((ext_vector_type(8)));

__device__ __forceinline__ u16 f2bf(float f){
  unsigned u = __builtin_bit_cast(unsigned, f);
  u += 0x7fffu + ((u >> 16) & 1u);            // round-to-nearest-even
  return (u16)(u >> 16);
}
__device__ __forceinline__ float bf2f(u16 b){
  unsigned u = ((unsigned)b) << 16;
  return __builtin_bit_cast(float, u);
}
__device__ __forceinline__ float sigm(float x){
  return 1.f / (1.f + __expf(-x));
}
__device__ __forceinline__ float tanh_fast(float x){
  return 2.f / (1.f + __expf(-2.f * x)) - 1.f;
}
// LDS A-tile swizzle: breaks the staging-write 64-way bank conflict.
// slot bits: m=[0:3], q=[4:5], kt=[6:11]. XOR low-3 bits with f(kt, q&1).
__device__ __forceinline__ int swz(int slot){
  return slot ^ ((slot >> 6) & 7) ^ (((slot >> 4) & 1) << 2);
}

#define KLIST(F) F(0) F(1) F(2) F(3) F(4) F(5) F(6) F(7) F(8) F(9) \
                 F(10) F(11) F(12) F(13) F(14) F(15) F(16) F(17) F(18) F(19)
#define SLIST(F) F(0) F(1) F(2) F(3) F(4)

// ---- pack weights into MFMA B-fragment order -------------------------------
// Wpack[ct][kt][lane][j]: ct in [0,256) covers gate-cols [ct*16, ct*16+16)
// (col = gate*1024 + n); element = W[k = kt*32 + (lane>>4)*8 + j][col = ct*16 + (lane&15)]
__global__ void prep_wpack(const float* __restrict__ Wfx, const float* __restrict__ Wix,
                           const float* __restrict__ Wgx, const float* __restrict__ Wox,
                           const float* __restrict__ Wfh, const float* __restrict__ Wih,
                           const float* __restrict__ Wgh, const float* __restrict__ Woh,
                           u16* __restrict__ Wpack){
  int id = blockIdx.x * 256 + threadIdx.x;    // [0, 655360)
  int lane = id & 63;
  int kt = (id >> 6) % NKT;
  int ct = id / (64 * NKT);
  int col = ct * 16 + (lane & 15);
  int g = col >> 10, n = col & 1023;
  int kbase = kt * 32 + (lane >> 4) * 8;
  const float* Wx = (g==0) ? Wfx : (g==1) ? Wix : (g==2) ? Wgx : Wox;
  const float* Wh = (g==0) ? Wfh : (g==1) ? Wih : (g==2) ? Wgh : Woh;
  u16x8 v;
  #pragma unroll
  for (int j = 0; j < 8; ++j){
    int k = kbase + j;
    float f = (k < DD) ? Wx[k * HH + n] : Wh[(k - DD) * HH + n];
    v[j] = f2bf(f);
  }
  *(u16x8*)(Wpack + (size_t)id * 8) = v;      // dst index == id (by construction)
}

// ---- transpose+cast x: xT[t][b][d] = bf16(x[b][t][d]) ----------------------
__global__ void prep_xT(const float* __restrict__ x, u16* __restrict__ xT){
  int id = blockIdx.x * 256 + threadIdx.x;    // [0, 1048576), 8 elems each
  int t = id >> 12;
  int b = (id >> 5) & 127;
  int d0 = (id & 31) * 8;
  const float* src = x + ((size_t)b * TT + t) * DD + d0;
  u16x8 v;
  #pragma unroll
  for (int j = 0; j < 8; ++j) v[j] = f2bf(src[j]);
  *(u16x8*)(xT + (size_t)id * 8) = v;
}

// ---- ALL 256 LSTM steps in one persistent cooperative kernel ---------------
__global__ __launch_bounds__(512, 2) void lstm_persist(
    const u16* __restrict__ xT,    // [T][B][D] bf16
    const u16* __restrict__ Wpack,
    u16* __restrict__ h0,          // [128][1024] bf16 (even-t input)
    u16* __restrict__ h1,          // [128][1024] bf16
    const float* __restrict__ bfv, const float* __restrict__ biv,
    const float* __restrict__ bgv, const float* __restrict__ bov,
    unsigned* __restrict__ barCnt){
  __shared__ u16x8 As4[NKT * 64];  // 40 KB: A tile in fragment order (swizzled)
  __shared__ float gLds[16][132];  // gate exchange (8.25 KB)
  __shared__ float pLds[16][132];  // K-half partial-sum exchange (8.25 KB)
  const int tid = threadIdx.x;
  const int n0 = blockIdx.x * 32;  // hidden-unit tile
  const int m0 = blockIdx.y * 16;  // batch-row tile
  unsigned* const myCnt = barCnt + blockIdx.y * 32;  // group barrier counter

  const int w = tid >> 6, lane = tid & 63, cr = lane & 15, q4 = lane >> 4;
  const int g  = w & 3;            // gate
  const int kh = w >> 2;           // K-half: kt in [kh*20, kh*20+20)
  const int ktBeg = kh * KHT;

  // ---- load this wave's weights into 40 NAMED u16x8 (160 VGPRs), ONCE ----
  const size_t ct0 = (size_t)(g * 64 + blockIdx.x * 2);  // 2 col-tiles of gate g
  const u16x8* Wp = (const u16x8*)Wpack;
  const u16x8* wq0 = Wp + ct0 * NKT * 64 + lane;
  const u16x8* wq1 = wq0 + NKT * 64;
#define DECLW(i) u16x8 w0_##i, w1_##i;
  KLIST(DECLW)
#define LOADW(i) w0_##i = wq0[(size_t)(ktBeg + (i)) * 64]; \
                 w1_##i = wq1[(size_t)(ktBeg + (i)) * 64];
  KLIST(LOADW)

  // bias (used by kh==0 waves in the combine)
  const float* bptr = (g==0) ? bfv : (g==1) ? biv : (g==2) ? bgv : bov;
  const float bias0 = bptr[n0 + cr], bias1 = bptr[n0 + 16 + cr];

  // ---- fixed per-thread staging geometry (named scalars, rule #20) ----
  // chunk ch -> row m = ch/160, k0 = (ch%160)*8 ; frag slot = kt*64 + 16*q + m
  unsigned isx = 0;
#define SGEOM(i) int so##i, sd##i; { int ch = tid + (i) * 512; \
    int m = ch / 160; int k0 = (ch - m * 160) * 8; \
    if (k0 < DD){ so##i = (m0 + m) * DD + k0; isx |= (1u << (i)); } \
    else        { so##i = (m0 + m) * HH + (k0 - DD); } \
    sd##i = swz((k0 >> 5) * 64 + 16 * ((k0 >> 3) & 3) + m); }
  SLIST(SGEOM)
#define STX(i) if ((isx >> (i)) & 1)   As4[sd##i] = *(const u16x8*)(xnext + so##i);
#define STH(i) if (!((isx >> (i)) & 1)) As4[sd##i] = *(const u16x8*)(hnext + so##i);

  // cell-update ownership is fixed: c lives in a register for all 256 steps
  const int crow = tid >> 5, cnn = tid & 31;
  const int gi = (m0 + crow) * HH + n0 + cnn;
  float cstate = 0.f;

  // prologue: stage x(t=0) and h(=0) into As4
  {
    const u16* xnext = xT;
    const u16* hnext = h0;
    SLIST(STX)
    SLIST(STH)
  }

  #pragma unroll 1
  for (int t = 0; t < TT; ++t){
    u16* hout = (t & 1) ? h0 : h1;
    __syncthreads();                 // A-tile staged (prologue or prev tail)

    f32x4 acc0 = {0.f, 0.f, 0.f, 0.f}, acc1 = {0.f, 0.f, 0.f, 0.f};
    u16x8 a0 = As4[swz(ktBeg * 64 + lane)];
    u16x8 a1 = As4[swz((ktBeg + 1) * 64 + lane)];
#define STEPK(i) { u16x8 ac = ((i) & 1) ? a1 : a0; \
    if ((i) + 2 < KHT){ \
      if ((i) & 1) a1 = As4[swz((ktBeg + (i) + 2) * 64 + lane)]; \
      else         a0 = As4[swz((ktBeg + (i) + 2) * 64 + lane)]; } \
    acc0 = __builtin_amdgcn_mfma_f32_16x16x32_bf16(__builtin_bit_cast(bf16x8, ac), \
             __builtin_bit_cast(bf16x8, w0_##i), acc0, 0, 0, 0); \
    acc1 = __builtin_amdgcn_mfma_f32_16x16x32_bf16(__builtin_bit_cast(bf16x8, ac), \
             __builtin_bit_cast(bf16x8, w1_##i), acc1, 0, 0, 0); }
    KLIST(STEPK)

    // combine K-halves (C/D layout: col=lane&15, row=q4*4+r)
    if (kh){
      #pragma unroll
      for (int r = 0; r < 4; ++r){
        pLds[q4 * 4 + r][g * 32 + cr]      = acc0[r];
        pLds[q4 * 4 + r][g * 32 + 16 + cr] = acc1[r];
      }
    }
    __syncthreads();                 // As4 reads done; pLds visible
    if (!kh){
      #pragma unroll
      for (int r = 0; r < 4; ++r){
        gLds[q4 * 4 + r][g * 32 + cr] =
            acc0[r] + pLds[q4 * 4 + r][g * 32 + cr] + bias0;
        gLds[q4 * 4 + r][g * 32 + 16 + cr] =
            acc1[r] + pLds[q4 * 4 + r][g * 32 + 16 + cr] + bias1;
      }
    }
    // stage next-step x early (h-independent) to overlap epilogue + barrier
    if (t + 1 < TT){
      const u16* xnext = xT + (size_t)(t + 1) * BB * DD;
      SLIST(STX)
    }
    __syncthreads();                 // gLds visible

    // fused LSTM cell update: 512 (row, hidden) units, 1 per thread
    {
      float fp = gLds[crow][cnn],      ip = gLds[crow][32 + cnn];
      float gp = gLds[crow][64 + cnn], op = gLds[crow][96 + cnn];
      float fs = sigm(fp);
      float is = sigm(ip);
      float gs = tanh_fast(gp);
      float os = sigm(op);
      cstate = gs * is + cstate * fs;
      hout[gi] = f2bf(tanh_fast(cstate) * os);
    }

    // ---- per-row-group barrier (32 blocks sharing blockIdx.y) ----
    if (t != TT - 1){
      __syncthreads();               // each wave drains its hout stores
      if (tid == 0){
        __threadfence();             // release: L2 writeback so peers see hout
        __hip_atomic_fetch_add(myCnt, 1u, __ATOMIC_RELAXED,
                               __HIP_MEMORY_SCOPE_AGENT);
        const unsigned tgt = (unsigned)(t + 1) * 32u;
        while (__hip_atomic_load(myCnt, __ATOMIC_RELAXED,
                                 __HIP_MEMORY_SCOPE_AGENT) < tgt)
          __builtin_amdgcn_s_sleep(1);
        __threadfence();             // acquire: invalidate stale h
      }
      __syncthreads();
      // stage next-step h (written by peers this step)
      const u16* hnext = hout;
      SLIST(STH)
    }
  }
}

// ---- out[b][c] = h_T[b] . Wph[:,c] + bp[c] ---------------------------------
__global__ void final_proj(const u16* __restrict__ h, const float* __restrict__ Wph,
                           const float* __restrict__ bp, float* __restrict__ out){
  __shared__ float red[10][256];
  int b = blockIdx.x, tid = threadIdx.x;
  float p[10];
  #pragma unroll
  for (int c = 0; c < 10; ++c) p[c] = 0.f;
  for (int k = tid; k < HH; k += 256){
    float hv = bf2f(h[b * HH + k]);
    const float* wr = Wph + (size_t)k * 10;
    #pragma unroll
    for (int c = 0; c < 10; ++c) p[c] += hv * wr[c];
  }
  #pragma unroll
  for (int c = 0; c < 10; ++c) red[c][tid] = p[c];
  __syncthreads();
  for (int s = 128; s > 0; s >>= 1){
    if (tid < s){
      #pragma unroll
      for (int c = 0; c < 10; ++c) red[c][tid] += red[c][tid + s];
    }
    __syncthreads();
  }
  if (tid < 10) out[b * 10 + tid] = red[tid][0] + bp[tid];
}

extern "C" void kernel_launch(void* const* d_in, const int* in_sizes, int n_in,
                              void* d_out, int out_size, void* d_ws, size_t ws_size,
                              hipStream_t stream){
  (void)in_sizes; (void)n_in; (void)out_size; (void)ws_size;
  const float* x   = (const float*)d_in[0];
  const float* Wfx = (const float*)d_in[1];
  const float* Wix = (const float*)d_in[2];
  const float* Wgx = (const float*)d_in[3];
  const float* Wox = (const float*)d_in[4];
  const float* Wfh = (const float*)d_in[5];
  const float* Wih = (const float*)d_in[6];
  const float* Wgh = (const float*)d_in[7];
  const float* Woh = (const float*)d_in[8];
  const float* bfv = (const float*)d_in[9];
  const float* biv = (const float*)d_in[10];
  const float* bgv = (const float*)d_in[11];
  const float* bov = (const float*)d_in[12];
  const float* Wph = (const float*)d_in[13];
  const float* bp  = (const float*)d_in[14];

  char* ws = (char*)d_ws;
  u16*  Wpack = (u16*)ws;                    // 10,485,760 B
  u16*  xT    = (u16*)(ws + 10485760);       // 16,777,216 B
  u16*  h0    = (u16*)(ws + 27262976);       //    262,144 B
  u16*  h1    = (u16*)(ws + 27525120);       //    262,144 B
  unsigned* barCnt = (unsigned*)(ws + 27787264);  // 1,024 B

  prep_wpack<<<2560, 256, 0, stream>>>(Wfx, Wix, Wgx, Wox, Wfh, Wih, Wgh, Woh, Wpack);
  prep_xT<<<4096, 256, 0, stream>>>(x, xT);
  hipMemsetAsync(h0, 0, 262144, stream);
  hipMemsetAsync(barCnt, 0, 1024, stream);

  void* args[] = {(void*)&xT, (void*)&Wpack, (void*)&h0, (void*)&h1,
                  (void*)&bfv, (void*)&biv, (void*)&bgv, (void*)&bov,
                  (void*)&barCnt};
  hipLaunchCooperativeKernel((const void*)lstm_persist, dim3(32, 8), dim3(512),
                             args, 0, stream);

  // t=255 (odd) wrote h0 -> final hidden state lives in h0
  final_proj<<<128, 256, 0, stream>>>(h0, Wph, bp, (float*)d_out);
}